// Round 4
// baseline (660.063 us; speedup 1.0000x reference)
//
#include <hip/hip_runtime.h>
#include <hip/hip_cooperative_groups.h>
#include <stdint.h>

namespace cg = cooperative_groups;

// ---------- types ----------
typedef __bf16 bf16x8 __attribute__((ext_vector_type(8)));
typedef float f32x4 __attribute__((ext_vector_type(4)));
typedef unsigned short u16x4 __attribute__((ext_vector_type(4)));

static __device__ __forceinline__ unsigned short f2bf(float f) {
    union { float f; unsigned u; } v; v.f = f;
    unsigned r = (v.u + 0x7FFFu + ((v.u >> 16) & 1u)) >> 16;  // RNE
    return (unsigned short)r;
}

// ---------- shared GEMM tile routine ----------
// D[m][n] = sum_k A[m*LDA+k] * B[n*LDB+k]; writes out[n*LDO+m] (+bias[m], relu)
// 128x64 tile, BK=64, 256 threads (4 waves 2x2: 64m x 32n per wave).
// LDS XOR swizzle: chunk(row,pos) at row*8 + (pos ^ (row&7)), 16B chunks.
template<bool BIAS, bool RELU, typename OT>
__device__ __forceinline__
void gemm_tile(const unsigned short* __restrict__ A, int LDA,
               const unsigned short* __restrict__ B, int LDB,
               OT* __restrict__ out, int LDO,
               const float* __restrict__ bias,
               int m0, int n0,
               unsigned short* As, unsigned short* Bs) {
    const int tid  = threadIdx.x;
    const int lane = tid & 63;
    const int wave = tid >> 6;
    const int quad = lane >> 4;
    const int l16  = lane & 15;
    const int wm   = wave & 1;
    const int wn   = wave >> 1;

    const int srow = tid >> 3;                 // 0..31
    const int spos = (tid & 7) ^ (srow & 7);
    const unsigned short* aG = A + (size_t)(m0 + srow) * LDA + spos * 8;
    const unsigned short* bG = B + (size_t)(n0 + srow) * LDB + spos * 8;
    char* aL = (char*)As + tid * 16;
    char* bL = (char*)Bs + tid * 16;

    f32x4 acc[4][2];
    #pragma unroll
    for (int i = 0; i < 4; ++i)
        #pragma unroll
        for (int j = 0; j < 2; ++j) {
            f32x4 z = {0.f, 0.f, 0.f, 0.f};
            acc[i][j] = z;
        }

    #pragma unroll 1
    for (int kk = 0; kk < 8; ++kk) {   // K=512, BK=64
        const int ko = kk * 64;
        #pragma unroll
        for (int r = 0; r < 4; ++r)
            __builtin_amdgcn_global_load_lds(
                (__attribute__((address_space(1))) void*)(uintptr_t)(aG + (size_t)(r * 32) * LDA + ko),
                (__attribute__((address_space(3))) void*)(aL + r * 4096), 16, 0, 0);
        #pragma unroll
        for (int r = 0; r < 2; ++r)
            __builtin_amdgcn_global_load_lds(
                (__attribute__((address_space(1))) void*)(uintptr_t)(bG + (size_t)(r * 32) * LDB + ko),
                (__attribute__((address_space(3))) void*)(bL + r * 4096), 16, 0, 0);
        __syncthreads();

        #pragma unroll
        for (int ks = 0; ks < 2; ++ks) {
            bf16x8 af[4], bfr[2];
            #pragma unroll
            for (int i = 0; i < 4; ++i) {
                const int row = wm * 64 + i * 16 + l16;
                const int idx = row * 8 + ((ks * 4 + quad) ^ (row & 7));
                af[i] = *(const bf16x8*)((const char*)As + idx * 16);
            }
            #pragma unroll
            for (int j = 0; j < 2; ++j) {
                const int row = wn * 32 + j * 16 + l16;
                const int idx = row * 8 + ((ks * 4 + quad) ^ (row & 7));
                bfr[j] = *(const bf16x8*)((const char*)Bs + idx * 16);
            }
            #pragma unroll
            for (int i = 0; i < 4; ++i)
                #pragma unroll
                for (int j = 0; j < 2; ++j)
                    acc[i][j] = __builtin_amdgcn_mfma_f32_16x16x32_bf16(af[i], bfr[j], acc[i][j], 0, 0, 0);
        }
        __syncthreads();
    }

    #pragma unroll
    for (int i = 0; i < 4; ++i) {
        const int mb = m0 + wm * 64 + i * 16 + quad * 4;
        f32x4 bb = {0.f, 0.f, 0.f, 0.f};
        if constexpr (BIAS) bb = *(const f32x4*)(bias + (mb - m0) + m0);
        #pragma unroll
        for (int j = 0; j < 2; ++j) {
            const int n = n0 + wn * 32 + j * 16 + l16;
            f32x4 v = acc[i][j];
            if constexpr (BIAS) v += bb;
            if constexpr (RELU) {
                v.x = v.x > 0.f ? v.x : 0.f;
                v.y = v.y > 0.f ? v.y : 0.f;
                v.z = v.z > 0.f ? v.z : 0.f;
                v.w = v.w > 0.f ? v.w : 0.f;
            }
            if constexpr (sizeof(OT) == 4) {
                *(f32x4*)((float*)out + (size_t)n * LDO + mb) = v;
            } else {
                u16x4 o;
                o.x = f2bf(v.x); o.y = f2bf(v.y); o.z = f2bf(v.z); o.w = f2bf(v.w);
                *(u16x4*)((unsigned short*)out + (size_t)n * LDO + mb) = o;
            }
        }
    }
}

// ---------- fused cooperative kernel: prep + 3x(feature GEMM, aggregate GEMM) ----
// 512 blocks x 256 threads, 2 blocks/CU. Each GEMM phase = 1024 tiles, 2/block.
__global__ __launch_bounds__(256, 2)
void fused_gcn(const float* __restrict__ X, const float* __restrict__ adj,
               const float* __restrict__ W0, const float* __restrict__ b0,
               const float* __restrict__ W1, const float* __restrict__ b1,
               const float* __restrict__ W2, const float* __restrict__ b2,
               float* __restrict__ out,
               unsigned short* __restrict__ bufH,
               unsigned short* __restrict__ adjB,
               unsigned short* __restrict__ tmpT,
               unsigned short* __restrict__ Wt) {
    cg::grid_group grid = cg::this_grid();
    __shared__ unsigned short As[128 * 64];   // 16 KB
    __shared__ unsigned short Bs[64 * 64];    //  8 KB

    // ---- phase 0: convert X, adj to bf16; transpose W0..W2 to bf16 ----
    {
        const int gt = blockIdx.x * 256 + threadIdx.x;   // 0..131071
        #pragma unroll 1
        for (int it = 0; it < 16; ++it) {
            const int i = it * 131072 + gt;
            f32x4 v = ((const f32x4*)X)[i];
            u16x4 o;
            o.x = f2bf(v.x); o.y = f2bf(v.y); o.z = f2bf(v.z); o.w = f2bf(v.w);
            ((u16x4*)bufH)[i] = o;
            f32x4 w = ((const f32x4*)adj)[i];
            u16x4 p;
            p.x = f2bf(w.x); p.y = f2bf(w.y); p.z = f2bf(w.z); p.w = f2bf(w.w);
            ((u16x4*)adjB)[i] = p;
        }
        float (*tileS)[33] = (float(*)[33])As;   // scratch overlay (4.2 KB of 16 KB)
        const int t = threadIdx.x;
        const int tx = t & 31, ty = t >> 5;      // 32 x 8
        #pragma unroll 1
        for (int tt = blockIdx.x; tt < 768; tt += 512) {
            const int z = tt >> 8;               // which W
            const int tile = tt & 255;
            const float* W = (z == 0) ? W0 : (z == 1) ? W1 : W2;
            unsigned short* dst = Wt + (size_t)z * (512 * 512);
            const int bx = (tile & 15) * 32, by = (tile >> 4) * 32;
            __syncthreads();
            #pragma unroll
            for (int r = 0; r < 32; r += 8)
                tileS[ty + r][tx] = W[(size_t)(by + ty + r) * 512 + (bx + tx)];
            __syncthreads();
            #pragma unroll
            for (int r = 0; r < 32; r += 8)
                dst[(size_t)(bx + ty + r) * 512 + (by + tx)] = f2bf(tileS[tx][ty + r]);
        }
    }
    grid.sync();

    // ---- layer 0 ----
    #pragma unroll 1
    for (int r = 0; r < 2; ++r) {   // feature: tmpT[e][gnode] = bufH @ W0
        const int tile = blockIdx.x * 2 + r;
        gemm_tile<false, false, unsigned short>(bufH, 512, Wt, 512, tmpT, 16384,
                                                nullptr, (tile >> 3) * 128, (tile & 7) * 64, As, Bs);
    }
    grid.sync();
    #pragma unroll 1
    for (int r = 0; r < 2; ++r) {   // aggregate: bufH[z][n][e] = relu(adj@sup + b0)
        const int tile = blockIdx.x * 2 + r;
        const int z = tile >> 5, mx = (tile >> 3) & 3, nx = tile & 7;
        gemm_tile<true, true, unsigned short>(tmpT + z * 512, 16384,
                                              adjB + (size_t)z * 262144, 512,
                                              bufH + (size_t)z * 262144, 512,
                                              b0, mx * 128, nx * 64, As, Bs);
    }
    grid.sync();

    // ---- layer 1 ----
    #pragma unroll 1
    for (int r = 0; r < 2; ++r) {
        const int tile = blockIdx.x * 2 + r;
        gemm_tile<false, false, unsigned short>(bufH, 512, Wt + 262144, 512, tmpT, 16384,
                                                nullptr, (tile >> 3) * 128, (tile & 7) * 64, As, Bs);
    }
    grid.sync();
    #pragma unroll 1
    for (int r = 0; r < 2; ++r) {
        const int tile = blockIdx.x * 2 + r;
        const int z = tile >> 5, mx = (tile >> 3) & 3, nx = tile & 7;
        gemm_tile<true, true, unsigned short>(tmpT + z * 512, 16384,
                                              adjB + (size_t)z * 262144, 512,
                                              bufH + (size_t)z * 262144, 512,
                                              b1, mx * 128, nx * 64, As, Bs);
    }
    grid.sync();

    // ---- layer 2 (no relu, fp32 out) ----
    #pragma unroll 1
    for (int r = 0; r < 2; ++r) {
        const int tile = blockIdx.x * 2 + r;
        gemm_tile<false, false, unsigned short>(bufH, 512, Wt + 2 * 262144, 512, tmpT, 16384,
                                                nullptr, (tile >> 3) * 128, (tile & 7) * 64, As, Bs);
    }
    grid.sync();
    #pragma unroll 1
    for (int r = 0; r < 2; ++r) {
        const int tile = blockIdx.x * 2 + r;
        const int z = tile >> 5, mx = (tile >> 3) & 3, nx = tile & 7;
        gemm_tile<true, false, float>(tmpT + z * 512, 16384,
                                      adjB + (size_t)z * 262144, 512,
                                      out + (size_t)z * 262144, 512,
                                      b2, mx * 128, nx * 64, As, Bs);
    }
}

// ================= fallback path (R3 structure) =================
__global__ void prep_kernel(const float* __restrict__ X,
                            const float* __restrict__ adj,
                            const float* __restrict__ W0,
                            const float* __restrict__ W1,
                            const float* __restrict__ W2,
                            unsigned short* __restrict__ bufH,
                            unsigned short* __restrict__ adjB,
                            unsigned short* __restrict__ Wt) {
    const int bid = blockIdx.x;
    const int t = threadIdx.x;
    if (bid < 16384) {
        const float* src = (bid < 8192) ? X : adj;
        unsigned short* dst = (bid < 8192) ? bufH : adjB;
        const int i = (bid & 8191) * 256 + t;
        f32x4 v = ((const f32x4*)src)[i];
        u16x4 o;
        o.x = f2bf(v.x); o.y = f2bf(v.y); o.z = f2bf(v.z); o.w = f2bf(v.w);
        ((u16x4*)dst)[i] = o;
    } else {
        const int wb = bid - 16384;
        const int z = wb >> 8;
        const int tile = wb & 255;
        const float* W = (z == 0) ? W0 : (z == 1) ? W1 : W2;
        unsigned short* dst = Wt + (size_t)z * (512 * 512);
        __shared__ float tileS[32][33];
        const int bx = (tile & 15) * 32, by = (tile >> 4) * 32;
        const int tx = t & 31, ty = t >> 5;
        #pragma unroll
        for (int r = 0; r < 32; r += 8)
            tileS[ty + r][tx] = W[(size_t)(by + ty + r) * 512 + (bx + tx)];
        __syncthreads();
        #pragma unroll
        for (int r = 0; r < 32; r += 8)
            dst[(size_t)(bx + ty + r) * 512 + (by + tx)] = f2bf(tileS[tx][ty + r]);
    }
}

template<int LDA, int LDB, int LDO, bool BIAS, bool RELU, typename OT>
__global__ __launch_bounds__(256, 2)
void gemm_abT_ct(const unsigned short* __restrict__ A,
                 const unsigned short* __restrict__ B,
                 OT* __restrict__ out, const float* __restrict__ bias,
                 long batchA, long batchB, long batchO) {
    __shared__ unsigned short As[128 * 64];
    __shared__ unsigned short Bs[64 * 64];
    gemm_tile<BIAS, RELU, OT>(A + (size_t)blockIdx.z * batchA, LDA,
                              B + (size_t)blockIdx.z * batchB, LDB,
                              out + (size_t)blockIdx.z * batchO, LDO,
                              bias, blockIdx.x * 128, blockIdx.y * 64, As, Bs);
}

extern "C" void kernel_launch(void* const* d_in, const int* in_sizes, int n_in,
                              void* d_out, int out_size, void* d_ws, size_t ws_size,
                              hipStream_t stream) {
    (void)in_sizes; (void)n_in; (void)out_size; (void)ws_size;
    const float* X   = (const float*)d_in[0];
    const float* adj = (const float*)d_in[1];
    const float* W0  = (const float*)d_in[2];
    const float* b0  = (const float*)d_in[3];
    const float* W1  = (const float*)d_in[4];
    const float* b1  = (const float*)d_in[5];
    const float* W2  = (const float*)d_in[6];
    const float* b2  = (const float*)d_in[7];
    float* out = (float*)d_out;

    char* ws = (char*)d_ws;
    const size_t SZ = 16777216;  // 32*512*512*2
    unsigned short* adjB = (unsigned short*)(ws);
    unsigned short* bufH = (unsigned short*)(ws + SZ);
    unsigned short* tmpT = (unsigned short*)(ws + 2 * SZ);
    unsigned short* Wt   = (unsigned short*)(ws + 3 * SZ);

    void* args[] = {(void*)&X, (void*)&adj, (void*)&W0, (void*)&b0,
                    (void*)&W1, (void*)&b1, (void*)&W2, (void*)&b2,
                    (void*)&out, (void*)&bufH, (void*)&adjB, (void*)&tmpT, (void*)&Wt};
    hipError_t err = hipLaunchCooperativeKernel((const void*)fused_gcn,
                                                dim3(512), dim3(256), args, 0, stream);
    if (err == hipSuccess) return;

    // fallback: multi-dispatch path
    const unsigned short* W0t = Wt;
    const unsigned short* W1t = Wt + 262144;
    const unsigned short* W2t = Wt + 2 * 262144;
    prep_kernel<<<16384 + 768, 256, 0, stream>>>(X, adj, W0, W1, W2, bufH, adjB, Wt);
    const long BATCH = 512L * 512L;
    gemm_abT_ct<512, 512, 16384, false, false, unsigned short>
        <<<dim3(128, 8, 1), 256, 0, stream>>>(bufH, W0t, tmpT, nullptr, 0, 0, 0);
    gemm_abT_ct<16384, 512, 512, true, true, unsigned short>
        <<<dim3(4, 8, 32), 256, 0, stream>>>(tmpT, adjB, bufH, b0, 512, BATCH, BATCH);
    gemm_abT_ct<512, 512, 16384, false, false, unsigned short>
        <<<dim3(128, 8, 1), 256, 0, stream>>>(bufH, W1t, tmpT, nullptr, 0, 0, 0);
    gemm_abT_ct<16384, 512, 512, true, true, unsigned short>
        <<<dim3(4, 8, 32), 256, 0, stream>>>(tmpT, adjB, bufH, b1, 512, BATCH, BATCH);
    gemm_abT_ct<512, 512, 16384, false, false, unsigned short>
        <<<dim3(128, 8, 1), 256, 0, stream>>>(bufH, W2t, tmpT, nullptr, 0, 0, 0);
    gemm_abT_ct<16384, 512, 512, true, false, float>
        <<<dim3(4, 8, 32), 256, 0, stream>>>(tmpT, adjB, out, b2, 512, BATCH, BATCH);
}